// Round 4
// baseline (582.259 us; speedup 1.0000x reference)
//
#include <hip/hip_runtime.h>
#include <cstdint>

#define N 8192
#define FIN 256
#define FOUT 128
#define ALPHA 0.2f
#define KS 8                 // global j-slices (one per wave)
#define JSL (N / KS)         // 1024 j's per wave
#define NSTEP (JSL / 32)     // 32 k-steps of 32 j's

typedef unsigned short u16;
typedef __attribute__((ext_vector_type(8))) short short8;
typedef __attribute__((ext_vector_type(4))) float floatx4;

__device__ __forceinline__ u16 bf16_rne(float f) {
  uint32_t u = __float_as_uint(f);
  u += 0x7fff + ((u >> 16) & 1);
  return (u16)(u >> 16);
}

// ---------------------------------------------------------------------------
// Kernel 1: h = x@W (fp32); write hT3 (bf16, tiled [jb][m][q][nt][8] so k_gat
// b-frags are 8 imm-offset loads off one pointer); src = h@a1, dst = h@a2.
// ---------------------------------------------------------------------------
__global__ __launch_bounds__(256) void k_proj(const float* __restrict__ x,
                                              const float* __restrict__ W,
                                              const float* __restrict__ a,
                                              u16* __restrict__ hT3,
                                              float* __restrict__ srcv,
                                              float* __restrict__ dstv) {
  __shared__ float xs[8 * FIN];                     // 8 KB
  __shared__ float partS[4][4], partD[4][4];
  const int t = threadIdx.x;
  const int R0 = blockIdx.x * 8;

  const float4* xv = (const float4*)(x + (size_t)R0 * FIN);
  float4* xsv = (float4*)xs;
  xsv[t] = xv[t];
  xsv[t + 256] = xv[t + 256];
  __syncthreads();

  const int c  = t & 127;           // output column
  const int rg = (t >> 7) * 4;      // row group base (wave-uniform)

  float acc[4] = {0.f, 0.f, 0.f, 0.f};
  float wa[4], wb[4];
  #pragma unroll
  for (int j = 0; j < 4; ++j) wa[j] = W[j * FOUT + c];
  #pragma unroll
  for (int j = 0; j < 4; ++j) wb[j] = W[(4 + j) * FOUT + c];

  for (int k4 = 0; k4 < FIN / 4; ++k4) {
    float wc[4];
    #pragma unroll
    for (int j = 0; j < 4; ++j) { wc[j] = wa[j]; wa[j] = wb[j]; }
    const int kn = (k4 + 2 < FIN / 4) ? k4 + 2 : k4;
    #pragma unroll
    for (int j = 0; j < 4; ++j) wb[j] = W[(kn * 4 + j) * FOUT + c];
    #pragma unroll
    for (int i = 0; i < 4; ++i) {
      const float4 xq = *(const float4*)&xs[(rg + i) * FIN + k4 * 4];
      acc[i] += xq.x * wc[0] + xq.y * wc[1] + xq.z * wc[2] + xq.w * wc[3];
    }
  }

  {
    const int j = R0 + rg;
    const int jb = j >> 5, q = (j >> 3) & 3, jj = j & 7;
    const int m = c & 15, nt = c >> 4;
    union { u16 u[4]; uint2 v; } pk;
    #pragma unroll
    for (int i = 0; i < 4; ++i) pk.u[i] = bf16_rne(acc[i]);
    *(uint2*)(hT3 + (size_t)(((jb * 16 + m) * 4 + q) * 8 + nt) * 8 + jj) = pk.v;
  }

  const float a1 = a[c], a2 = a[FOUT + c];
  float s4[4], d4[4];
  #pragma unroll
  for (int i = 0; i < 4; ++i) { s4[i] = acc[i] * a1; d4[i] = acc[i] * a2; }
  #pragma unroll
  for (int off = 32; off > 0; off >>= 1) {
    #pragma unroll
    for (int i = 0; i < 4; ++i) {
      s4[i] += __shfl_down(s4[i], off);
      d4[i] += __shfl_down(d4[i], off);
    }
  }
  const int wv = t >> 6, lane = t & 63;
  if (lane == 0) {
    #pragma unroll
    for (int i = 0; i < 4; ++i) { partS[wv][i] = s4[i]; partD[wv][i] = d4[i]; }
  }
  __syncthreads();
  if (t < 16) {
    const int i = t & 3, rg2 = (t >> 2) & 1, which = t >> 3;
    if (which == 0) srcv[R0 + rg2 * 4 + i] = partS[rg2*2][i] + partS[rg2*2+1][i];
    else            dstv[R0 + rg2 * 4 + i] = partD[rg2*2][i] + partD[rg2*2+1][i];
  }
}

// ---------------------------------------------------------------------------
// Kernel 2: wave-independent fused GAT. Each wave: 16 rows x 128 cols over a
// 1024-j slice; lane(q,m) computes p[row m][q*8..+8] in registers (= MFMA
// A-frag layout) -> 8 MFMAs per 32-j step. Software pipeline is a manual
// 2x-unroll with NAMED double-buffer registers (round 3's abuf[i&1] dynamic
// index demoted the pipeline to scratch: VGPR_Count 52, 104 MB scratch
// writes). adj+dst prefetch distance-2; b-frags issued before the p-compute
// VALU block so L1/L2 latency hides under it. No barriers in the loop.
// ---------------------------------------------------------------------------
__global__ __launch_bounds__(256, 4) void k_gat(const int* __restrict__ adj,
                                                const u16* __restrict__ hT3,
                                                const float* __restrict__ srcv,
                                                const float* __restrict__ dstv,
                                                float* __restrict__ P,
                                                float* __restrict__ lp) {
  __shared__ float redP[2][16 * FOUT];    // 16 KB
  __shared__ float redL[2][16];
  const int t = threadIdx.x;
  const int wv = t >> 6, lane = t & 63;
  const int q = lane >> 4, m = lane & 15;
  const int bm = blockIdx.x & 255;
  const int jp = blockIdx.x >> 8;         // 0..3 (stored partial index)
  const int sp = wv >> 1;                 // strip within pair
  const int jh = wv & 1;                  // j-half within pair
  const int R0 = (bm * 2 + sp) * 16;
  const int j0 = (jp * 2 + jh) * JSL;

  const float srcm = srcv[R0 + m];
  const int*   adjp = adj + (size_t)(R0 + m) * N + j0 + q * 8;
  const float* dstp = dstv + j0 + q * 8;
  const u16*   hp   = hT3 + (size_t)(j0 >> 5) * 4096 + (m * 4 + q) * 64;

  floatx4 acc[8];
  #pragma unroll
  for (int nt = 0; nt < 8; ++nt) acc[nt] = (floatx4){0.f, 0.f, 0.f, 0.f};
  float lsum = 0.f;

  // one pipeline step: p-compute from pre-arrived regs + 8 MFMAs
  auto do_step = [&](int i, const int4& A0, const int4& A1,
                     const float4& D0, const float4& D1) {
    const u16* hpi = hp + (size_t)i * 4096;
    short8 bf[8];
    #pragma unroll
    for (int nt = 0; nt < 8; ++nt) bf[nt] = *(const short8*)(hpi + nt * 8);

    const int   ai[8] = {A0.x, A0.y, A0.z, A0.w, A1.x, A1.y, A1.z, A1.w};
    const float df[8] = {D0.x, D0.y, D0.z, D0.w, D1.x, D1.y, D1.z, D1.w};
    union { u16 u[8]; short8 s; } pk;
    #pragma unroll
    for (int e = 0; e < 8; ++e) {
      float v = srcm + df[e];
      v = fmaxf(v, ALPHA * v);              // leaky_relu, 2 insts
      const float p = ai[e] > 0 ? __expf(v) : 0.f;
      lsum += p;
      pk.u[e] = bf16_rne(p);
    }
    #pragma unroll
    for (int nt = 0; nt < 8; ++nt)
      acc[nt] = __builtin_amdgcn_mfma_f32_16x16x32_bf16(pk.s, bf[nt], acc[nt], 0, 0, 0);
  };

  // prologue: fill both named buffers (steps 0 and 1)
  int4   aA0 = *(const int4*)(adjp),      aA1 = *(const int4*)(adjp + 4);
  float4 dA0 = *(const float4*)(dstp),    dA1 = *(const float4*)(dstp + 4);
  int4   aB0 = *(const int4*)(adjp + 32), aB1 = *(const int4*)(adjp + 36);
  float4 dB0 = *(const float4*)(dstp + 32), dB1 = *(const float4*)(dstp + 36);

  for (int i = 0; i < NSTEP; i += 2) {
    // ---- even step: consume A buffer, refill A for step i+2
    {
      const int4 cA0 = aA0, cA1 = aA1;
      const float4 cD0 = dA0, cD1 = dA1;
      const int nx = (i + 2 < NSTEP) ? i + 2 : i;
      aA0 = *(const int4*)(adjp + nx * 32);
      aA1 = *(const int4*)(adjp + nx * 32 + 4);
      dA0 = *(const float4*)(dstp + nx * 32);
      dA1 = *(const float4*)(dstp + nx * 32 + 4);
      do_step(i, cA0, cA1, cD0, cD1);
    }
    // ---- odd step: consume B buffer, refill B for step i+3
    {
      const int4 cB0 = aB0, cB1 = aB1;
      const float4 cD0 = dB0, cD1 = dB1;
      const int nx = (i + 3 < NSTEP) ? i + 3 : i + 1;
      aB0 = *(const int4*)(adjp + nx * 32);
      aB1 = *(const int4*)(adjp + nx * 32 + 4);
      dB0 = *(const float4*)(dstp + nx * 32);
      dB1 = *(const float4*)(dstp + nx * 32 + 4);
      do_step(i + 1, cB0, cB1, cD0, cD1);
    }
  }

  // row-sum: reduce over the 4 q-lanes sharing row m
  lsum += __shfl_xor(lsum, 16);
  lsum += __shfl_xor(lsum, 32);

  // pair-reduce the two j-halves (waves {0,1} -> strip 0, {2,3} -> strip 1)
  if (jh == 1) {
    float* rp = redP[sp];
    #pragma unroll
    for (int nt = 0; nt < 8; ++nt)
      #pragma unroll
      for (int ri = 0; ri < 4; ++ri)
        rp[(q * 4 + ri) * FOUT + nt * 16 + m] = acc[nt][ri];
    if (lane < 16) redL[sp][lane] = lsum;
  }
  __syncthreads();
  if (jh == 0) {
    const float* rp = redP[sp];
    float* Pp = P + ((size_t)jp * N + R0) * FOUT;
    #pragma unroll
    for (int nt = 0; nt < 8; ++nt)
      #pragma unroll
      for (int ri = 0; ri < 4; ++ri) {
        const int idx = (q * 4 + ri) * FOUT + nt * 16 + m;
        Pp[idx] = acc[nt][ri] + rp[idx];
      }
    if (lane < 16) lp[(size_t)jp * N + R0 + lane] = lsum + redL[sp][lane];
  }
}

// ---------------------------------------------------------------------------
// Kernel 3: sum 4 partials, normalize by row-sum. ~20 MB traffic.
// ---------------------------------------------------------------------------
__global__ __launch_bounds__(256) void k_norm(const float* __restrict__ P,
                                              const float* __restrict__ lp,
                                              float* __restrict__ out) {
  const int idx = blockIdx.x * 256 + threadIdx.x;   // 0 .. N*FOUT/4-1
  const int rr = idx >> 5;
  const int c4 = (idx & 31) * 4;
  const float l = lp[rr] + lp[N + rr] + lp[2 * N + rr] + lp[3 * N + rr];
  const float inv = 1.0f / l;
  float4 s = {0.f, 0.f, 0.f, 0.f};
  #pragma unroll
  for (int jp = 0; jp < 4; ++jp) {
    const float4 p = *(const float4*)(P + ((size_t)jp * N + rr) * FOUT + c4);
    s.x += p.x; s.y += p.y; s.z += p.z; s.w += p.w;
  }
  s.x *= inv; s.y *= inv; s.z *= inv; s.w *= inv;
  *(float4*)(out + (size_t)rr * FOUT + c4) = s;
}

extern "C" void kernel_launch(void* const* d_in, const int* in_sizes, int n_in,
                              void* d_out, int out_size, void* d_ws, size_t ws_size,
                              hipStream_t stream) {
  const float* x   = (const float*)d_in[0];
  const int*   adj = (const int*)d_in[1];
  const float* W   = (const float*)d_in[2];
  const float* a   = (const float*)d_in[3];
  float* out = (float*)d_out;

  char* ws = (char*)d_ws;
  u16*   hT3  = (u16*)ws;     ws += (size_t)FOUT * N * sizeof(u16);            // 2 MB
  float* srcv = (float*)ws;   ws += (size_t)N * sizeof(float);
  float* dstv = (float*)ws;   ws += (size_t)N * sizeof(float);
  float* P    = (float*)ws;   ws += (size_t)4 * N * FOUT * sizeof(float);      // 16 MB
  float* lp   = (float*)ws;   ws += (size_t)4 * N * sizeof(float);

  k_proj<<<N / 8, 256, 0, stream>>>(x, W, a, hT3, srcv, dstv);
  k_gat <<<1024, 256, 0, stream>>>(adj, hT3, srcv, dstv, P, lp);
  k_norm<<<(N * FOUT / 4) / 256, 256, 0, stream>>>(P, lp, out);
}

// Round 5
// 476.392 us; speedup vs baseline: 1.2222x; 1.2222x over previous
//
#include <hip/hip_runtime.h>
#include <cstdint>

#define N 8192
#define FIN 256
#define FOUT 128
#define ALPHA 0.2f
#define KS 8                 // global j-slices (one per wave)
#define JSL (N / KS)         // 1024 j's per wave
#define NSTEP (JSL / 32)     // 32 k-steps of 32 j's

typedef unsigned short u16;
typedef __attribute__((ext_vector_type(8))) short short8;
typedef __attribute__((ext_vector_type(4))) float floatx4;

__device__ __forceinline__ u16 bf16_rne(float f) {
  uint32_t u = __float_as_uint(f);
  u += 0x7fff + ((u >> 16) & 1);
  return (u16)(u >> 16);
}

// ---------------------------------------------------------------------------
// Kernel 1: h = x@W (fp32); write hT3 (bf16) tiled [jb][nt][m*4+q][8] so each
// k_gat b-frag load instruction is CONTIGUOUS 1 KB across the wave (round 4's
// [jb][m][q][nt][8] put lanes at stride 128 B -> 64 cache-line transactions
// per load instruction -> TA/L1 request-rate bound). Also src/dst = h@a1/a2.
// ---------------------------------------------------------------------------
__global__ __launch_bounds__(256) void k_proj(const float* __restrict__ x,
                                              const float* __restrict__ W,
                                              const float* __restrict__ a,
                                              u16* __restrict__ hT3,
                                              float* __restrict__ srcv,
                                              float* __restrict__ dstv) {
  __shared__ float xs[8 * FIN];                     // 8 KB
  __shared__ float partS[4][4], partD[4][4];
  const int t = threadIdx.x;
  const int R0 = blockIdx.x * 8;

  const float4* xv = (const float4*)(x + (size_t)R0 * FIN);
  float4* xsv = (float4*)xs;
  xsv[t] = xv[t];
  xsv[t + 256] = xv[t + 256];
  __syncthreads();

  const int c  = t & 127;           // output column
  const int rg = (t >> 7) * 4;      // row group base (wave-uniform)

  float acc[4] = {0.f, 0.f, 0.f, 0.f};
  float wa[4], wb[4];
  #pragma unroll
  for (int j = 0; j < 4; ++j) wa[j] = W[j * FOUT + c];
  #pragma unroll
  for (int j = 0; j < 4; ++j) wb[j] = W[(4 + j) * FOUT + c];

  for (int k4 = 0; k4 < FIN / 4; ++k4) {
    float wc[4];
    #pragma unroll
    for (int j = 0; j < 4; ++j) { wc[j] = wa[j]; wa[j] = wb[j]; }
    const int kn = (k4 + 2 < FIN / 4) ? k4 + 2 : k4;
    #pragma unroll
    for (int j = 0; j < 4; ++j) wb[j] = W[(kn * 4 + j) * FOUT + c];
    #pragma unroll
    for (int i = 0; i < 4; ++i) {
      const float4 xq = *(const float4*)&xs[(rg + i) * FIN + k4 * 4];
      acc[i] += xq.x * wc[0] + xq.y * wc[1] + xq.z * wc[2] + xq.w * wc[3];
    }
  }

  {
    const int j = R0 + rg;                 // 4 consecutive j in one q-octet
    const int jb = j >> 5, q = (j >> 3) & 3, jj = j & 7;
    const int m = c & 15, nt = c >> 4;
    union { u16 u[4]; uint2 v; } pk;
    #pragma unroll
    for (int i = 0; i < 4; ++i) pk.u[i] = bf16_rne(acc[i]);
    *(uint2*)(hT3 + (size_t)(((jb * 8 + nt) * 64) + (m * 4 + q)) * 8 + jj) = pk.v;
  }

  const float a1 = a[c], a2 = a[FOUT + c];
  float s4[4], d4[4];
  #pragma unroll
  for (int i = 0; i < 4; ++i) { s4[i] = acc[i] * a1; d4[i] = acc[i] * a2; }
  #pragma unroll
  for (int off = 32; off > 0; off >>= 1) {
    #pragma unroll
    for (int i = 0; i < 4; ++i) {
      s4[i] += __shfl_down(s4[i], off);
      d4[i] += __shfl_down(d4[i], off);
    }
  }
  const int wv = t >> 6, lane = t & 63;
  if (lane == 0) {
    #pragma unroll
    for (int i = 0; i < 4; ++i) { partS[wv][i] = s4[i]; partD[wv][i] = d4[i]; }
  }
  __syncthreads();
  if (t < 16) {
    const int i = t & 3, rg2 = (t >> 2) & 1, which = t >> 3;
    if (which == 0) srcv[R0 + rg2 * 4 + i] = partS[rg2*2][i] + partS[rg2*2+1][i];
    else            dstv[R0 + rg2 * 4 + i] = partD[rg2*2][i] + partD[rg2*2+1][i];
  }
}

// ---------------------------------------------------------------------------
// Kernel 2: wave-independent fused GAT. Per 32-j step, STRICT issue order:
//   (1) 8 contiguous 1-KB b-frag loads  (2) distance-2 adj/dst refills
//   (3) p-compute VALU                  (4) 8 MFMAs
// so the MFMA's s_waitcnt is vmcnt(4) and refills stay in flight (round 4
// issued refills BEFORE bf -> vmcnt(0) drained the pipeline every step).
// Named double-buffer regs only (no dynamic indexing -> no scratch).
// ---------------------------------------------------------------------------
__global__ __launch_bounds__(256, 3) void k_gat(const int* __restrict__ adj,
                                                const u16* __restrict__ hT3,
                                                const float* __restrict__ srcv,
                                                const float* __restrict__ dstv,
                                                float* __restrict__ P,
                                                float* __restrict__ lp) {
  __shared__ float redP[2][16 * FOUT];    // 16 KB
  __shared__ float redL[2][16];
  const int t = threadIdx.x;
  const int wv = t >> 6, lane = t & 63;
  const int q = lane >> 4, m = lane & 15;
  const int bm = blockIdx.x & 255;
  const int jp = blockIdx.x >> 8;         // 0..3 (stored partial index)
  const int sp = wv >> 1;                 // strip within pair
  const int jh = wv & 1;                  // j-half within pair
  const int R0 = (bm * 2 + sp) * 16;
  const int j0 = (jp * 2 + jh) * JSL;

  const float srcm = srcv[R0 + m];
  const int*   adjp = adj + (size_t)(R0 + m) * N + j0 + q * 8;
  const float* dstp = dstv + j0 + q * 8;
  // contiguous-per-instruction b-frag base: lane offset (m*4+q)*16 B
  const u16*   hpl  = hT3 + (size_t)(j0 >> 5) * 4096 + (size_t)(m * 4 + q) * 8;

  floatx4 acc[8];
  #pragma unroll
  for (int nt = 0; nt < 8; ++nt) acc[nt] = (floatx4){0.f, 0.f, 0.f, 0.f};
  float lsum = 0.f;

  // prologue: fill both named prefetch buffers (steps 0 and 1)
  int4   aA0 = *(const int4*)(adjp),        aA1 = *(const int4*)(adjp + 4);
  float4 dA0 = *(const float4*)(dstp),      dA1 = *(const float4*)(dstp + 4);
  int4   aB0 = *(const int4*)(adjp + 32),   aB1 = *(const int4*)(adjp + 36);
  float4 dB0 = *(const float4*)(dstp + 32), dB1 = *(const float4*)(dstp + 36);

  #define GAT_STEP(I, A0_, A1_, D0_, D1_, NX)                                  \
  {                                                                            \
    /* (1) b-frags: 8 x contiguous 1 KB */                                     \
    const u16* hpi = hpl + (size_t)(I) * 4096;                                 \
    short8 bf0 = *(const short8*)(hpi);                                        \
    short8 bf1 = *(const short8*)(hpi + 512);                                  \
    short8 bf2 = *(const short8*)(hpi + 1024);                                 \
    short8 bf3 = *(const short8*)(hpi + 1536);                                 \
    short8 bf4 = *(const short8*)(hpi + 2048);                                 \
    short8 bf5 = *(const short8*)(hpi + 2560);                                 \
    short8 bf6 = *(const short8*)(hpi + 3072);                                 \
    short8 bf7 = *(const short8*)(hpi + 3584);                                 \
    const int4   cA0 = A0_, cA1 = A1_;                                         \
    const float4 cD0 = D0_, cD1 = D1_;                                         \
    /* (2) refill this buffer for step I+2 */                                  \
    A0_ = *(const int4*)(adjp + (NX) * 32);                                    \
    A1_ = *(const int4*)(adjp + (NX) * 32 + 4);                                \
    D0_ = *(const float4*)(dstp + (NX) * 32);                                  \
    D1_ = *(const float4*)(dstp + (NX) * 32 + 4);                              \
    /* (3) p-compute */                                                        \
    const int   ai[8] = {cA0.x, cA0.y, cA0.z, cA0.w, cA1.x, cA1.y, cA1.z, cA1.w}; \
    const float df[8] = {cD0.x, cD0.y, cD0.z, cD0.w, cD1.x, cD1.y, cD1.z, cD1.w}; \
    union { u16 u[8]; short8 s; } pk;                                          \
    _Pragma("unroll")                                                          \
    for (int e = 0; e < 8; ++e) {                                              \
      float v = srcm + df[e];                                                  \
      v = fmaxf(v, ALPHA * v);                                                 \
      const float p = ai[e] > 0 ? __expf(v) : 0.f;                             \
      lsum += p;                                                               \
      pk.u[e] = bf16_rne(p);                                                   \
    }                                                                          \
    /* (4) MFMAs */                                                            \
    acc[0] = __builtin_amdgcn_mfma_f32_16x16x32_bf16(pk.s, bf0, acc[0], 0, 0, 0); \
    acc[1] = __builtin_amdgcn_mfma_f32_16x16x32_bf16(pk.s, bf1, acc[1], 0, 0, 0); \
    acc[2] = __builtin_amdgcn_mfma_f32_16x16x32_bf16(pk.s, bf2, acc[2], 0, 0, 0); \
    acc[3] = __builtin_amdgcn_mfma_f32_16x16x32_bf16(pk.s, bf3, acc[3], 0, 0, 0); \
    acc[4] = __builtin_amdgcn_mfma_f32_16x16x32_bf16(pk.s, bf4, acc[4], 0, 0, 0); \
    acc[5] = __builtin_amdgcn_mfma_f32_16x16x32_bf16(pk.s, bf5, acc[5], 0, 0, 0); \
    acc[6] = __builtin_amdgcn_mfma_f32_16x16x32_bf16(pk.s, bf6, acc[6], 0, 0, 0); \
    acc[7] = __builtin_amdgcn_mfma_f32_16x16x32_bf16(pk.s, bf7, acc[7], 0, 0, 0); \
  }

  for (int i = 0; i < NSTEP; i += 2) {
    const int nxA = (i + 2 < NSTEP) ? i + 2 : i;
    GAT_STEP(i, aA0, aA1, dA0, dA1, nxA)
    const int nxB = (i + 3 < NSTEP) ? i + 3 : i + 1;
    GAT_STEP(i + 1, aB0, aB1, dB0, dB1, nxB)
  }
  #undef GAT_STEP

  // row-sum: reduce over the 4 q-lanes sharing row m
  lsum += __shfl_xor(lsum, 16);
  lsum += __shfl_xor(lsum, 32);

  // pair-reduce the two j-halves (waves {0,1} -> strip 0, {2,3} -> strip 1)
  if (jh == 1) {
    float* rp = redP[sp];
    #pragma unroll
    for (int nt = 0; nt < 8; ++nt)
      #pragma unroll
      for (int ri = 0; ri < 4; ++ri)
        rp[(q * 4 + ri) * FOUT + nt * 16 + m] = acc[nt][ri];
    if (lane < 16) redL[sp][lane] = lsum;
  }
  __syncthreads();
  if (jh == 0) {
    const float* rp = redP[sp];
    float* Pp = P + ((size_t)jp * N + R0) * FOUT;
    #pragma unroll
    for (int nt = 0; nt < 8; ++nt)
      #pragma unroll
      for (int ri = 0; ri < 4; ++ri) {
        const int idx = (q * 4 + ri) * FOUT + nt * 16 + m;
        Pp[idx] = acc[nt][ri] + rp[idx];
      }
    if (lane < 16) lp[(size_t)jp * N + R0 + lane] = lsum + redL[sp][lane];
  }
}

// ---------------------------------------------------------------------------
// Kernel 3: sum 4 partials, normalize by row-sum. ~20 MB traffic.
// ---------------------------------------------------------------------------
__global__ __launch_bounds__(256) void k_norm(const float* __restrict__ P,
                                              const float* __restrict__ lp,
                                              float* __restrict__ out) {
  const int idx = blockIdx.x * 256 + threadIdx.x;   // 0 .. N*FOUT/4-1
  const int rr = idx >> 5;
  const int c4 = (idx & 31) * 4;
  const float l = lp[rr] + lp[N + rr] + lp[2 * N + rr] + lp[3 * N + rr];
  const float inv = 1.0f / l;
  float4 s = {0.f, 0.f, 0.f, 0.f};
  #pragma unroll
  for (int jp = 0; jp < 4; ++jp) {
    const float4 p = *(const float4*)(P + ((size_t)jp * N + rr) * FOUT + c4);
    s.x += p.x; s.y += p.y; s.z += p.z; s.w += p.w;
  }
  s.x *= inv; s.y *= inv; s.z *= inv; s.w *= inv;
  *(float4*)(out + (size_t)rr * FOUT + c4) = s;
}

extern "C" void kernel_launch(void* const* d_in, const int* in_sizes, int n_in,
                              void* d_out, int out_size, void* d_ws, size_t ws_size,
                              hipStream_t stream) {
  const float* x   = (const float*)d_in[0];
  const int*   adj = (const int*)d_in[1];
  const float* W   = (const float*)d_in[2];
  const float* a   = (const float*)d_in[3];
  float* out = (float*)d_out;

  char* ws = (char*)d_ws;
  u16*   hT3  = (u16*)ws;     ws += (size_t)FOUT * N * sizeof(u16);            // 2 MB
  float* srcv = (float*)ws;   ws += (size_t)N * sizeof(float);
  float* dstv = (float*)ws;   ws += (size_t)N * sizeof(float);
  float* P    = (float*)ws;   ws += (size_t)4 * N * FOUT * sizeof(float);      // 16 MB
  float* lp   = (float*)ws;   ws += (size_t)4 * N * sizeof(float);

  k_proj<<<N / 8, 256, 0, stream>>>(x, W, a, hT3, srcv, dstv);
  k_gat <<<1024, 256, 0, stream>>>(adj, hT3, srcv, dstv, P, lp);
  k_norm<<<(N * FOUT / 4) / 256, 256, 0, stream>>>(P, lp, out);
}